// Round 1
// baseline (3239.108 us; speedup 1.0000x reference)
//
#include <hip/hip_runtime.h>
#include <math.h>

// Modulated conv2d (StyleGAN2): B=8, I=O=512, H=W=64, K=3, fp32.
// R1: correct fp32 baseline. style GEMV -> w2 -> demod d -> direct conv.
// Conv: weights read via wave-uniform indices (scalar loads), x staged in LDS.

#define BATCH 8
#define CIN   512
#define COUT  512
#define HH    64
#define WW    64
#define ICH   16   // input channels staged per LDS chunk

// ---------- style[b][i] = (dlatents[b] . dense_w[i]) / sqrt(512) + dense_b[i]
// one wave per (b,i); 4096 waves = 1024 blocks x 256 threads
__global__ void style_kernel(const float* __restrict__ dl,
                             const float* __restrict__ dw,
                             const float* __restrict__ db,
                             float* __restrict__ style) {
    int gw   = (blockIdx.x * blockDim.x + threadIdx.x) >> 6;
    int lane = threadIdx.x & 63;
    int b = gw >> 9;          // /512
    int i = gw & 511;
    const float* dlp = dl + b * 512;
    const float* dwp = dw + (size_t)i * 512;
    float acc = 0.f;
    #pragma unroll
    for (int d = 0; d < 512; d += 64) acc += dlp[d + lane] * dwp[d + lane];
    #pragma unroll
    for (int off = 32; off > 0; off >>= 1) acc += __shfl_down(acc, off, 64);
    if (lane == 0) style[b * 512 + i] = acc * (1.0f / sqrtf(512.0f)) + db[i];
}

// ---------- w2[o][i] = sum_tap w[o][i][tap]^2   (262144 threads)
__global__ void w2_kernel(const float* __restrict__ w, float* __restrict__ w2) {
    int idx = blockIdx.x * blockDim.x + threadIdx.x;   // o*512+i
    const float* wp = w + (size_t)idx * 9;
    float s = 0.f;
    #pragma unroll
    for (int t = 0; t < 9; t++) s += wp[t] * wp[t];
    w2[idx] = s;
}

// ---------- d[b][o] = rsqrt( (1/4608) * sum_i w2[o][i]*style[b][i]^2 + 1e-8 )
// one wave per (b,o)
__global__ void demod_kernel(const float* __restrict__ w2,
                             const float* __restrict__ style,
                             float* __restrict__ dvec) {
    int gw   = (blockIdx.x * blockDim.x + threadIdx.x) >> 6;
    int lane = threadIdx.x & 63;
    int b = gw >> 9;
    int o = gw & 511;
    const float* w2p = w2 + (size_t)o * 512;
    const float* stp = style + b * 512;
    float acc = 0.f;
    #pragma unroll
    for (int i = 0; i < 512; i += 64) {
        float s = stp[i + lane];
        acc += w2p[i + lane] * s * s;
    }
    #pragma unroll
    for (int off = 32; off > 0; off >>= 1) acc += __shfl_down(acc, off, 64);
    if (lane == 0)
        dvec[b * 512 + o] = rsqrtf(acc * (1.0f / 4608.0f) + 1e-8f);
}

// ---------- direct conv: block = (b, og[16 outs], 4 rows x 64 cols)
// out[b,o,h,c] = cs * d[b,o] * sum_{i,tap} w[o,i,tap] * x[b,i,h+dy,c+dx]*style[b,i]
__global__ __launch_bounds__(256) void conv_kernel(
        const float* __restrict__ x, const float* __restrict__ w,
        const float* __restrict__ style, const float* __restrict__ dvec,
        float* __restrict__ out) {
    __shared__ float xs[ICH][6][68];   // 6 rows (4 outs + halo), 66 cols used, pad->68
    const int tid = threadIdx.x;
    const int col = tid & 63;
    const int r   = tid >> 6;          // 0..3
    const int hq  = blockIdx.x;        // 0..15
    const int og  = blockIdx.y;        // 0..31
    const int b   = blockIdx.z;        // 0..7
    const int h0  = hq * 4;
    const int h   = h0 + r;

    float acc[16];
    #pragma unroll
    for (int i = 0; i < 16; i++) acc[i] = 0.f;

    for (int ic = 0; ic < CIN; ic += ICH) {
        __syncthreads();
        // stage x*style tile: ICH channels x 6 rows x 66 cols (zero halo)
        for (int idx = tid; idx < ICH * 6 * 66; idx += 256) {
            int ii  = idx / (6 * 66);
            int rem = idx - ii * (6 * 66);
            int rr  = rem / 66;
            int cc  = rem - rr * 66;
            int gh  = h0 - 1 + rr;
            int gc  = cc - 1;
            float v = 0.f;
            if ((unsigned)gh < 64u && (unsigned)gc < 64u)
                v = x[(((size_t)b * CIN + ic + ii) * HH + gh) * WW + gc]
                    * style[b * CIN + ic + ii];
            xs[ii][rr][cc] = v;
        }
        __syncthreads();

        for (int ii = 0; ii < ICH; ii++) {
            float xv[9];
            #pragma unroll
            for (int t = 0; t < 9; t++)
                xv[t] = xs[ii][r + t / 3][col + t % 3];
            // wave-uniform weight pointer -> scalar loads
            const float* wp = w + ((size_t)og * 16 * CIN + (ic + ii)) * 9;
            #pragma unroll
            for (int oo = 0; oo < 16; oo++) {
                #pragma unroll
                for (int t = 0; t < 9; t++)
                    acc[oo] += xv[t] * wp[(size_t)oo * (CIN * 9) + t];
            }
        }
    }

    const float cs = 1.0f / sqrtf(4608.0f);   // conv_scale
    #pragma unroll
    for (int oo = 0; oo < 16; oo++) {
        int o = og * 16 + oo;
        out[(((size_t)b * COUT + o) * HH + h) * WW + col]
            = acc[oo] * cs * dvec[b * COUT + o];
    }
}

extern "C" void kernel_launch(void* const* d_in, const int* in_sizes, int n_in,
                              void* d_out, int out_size, void* d_ws, size_t ws_size,
                              hipStream_t stream) {
    const float* x  = (const float*)d_in[0];   // [8,512,64,64]
    const float* dl = (const float*)d_in[1];   // [8,512]
    const float* w  = (const float*)d_in[2];   // [512,512,3,3]
    const float* dw = (const float*)d_in[3];   // [512,512]
    const float* db = (const float*)d_in[4];   // [512]
    float* out = (float*)d_out;

    float* ws    = (float*)d_ws;
    float* style = ws;                 // 4096 floats
    float* dvec  = ws + 4096;          // 4096 floats
    float* w2    = ws + 8192;          // 262144 floats  (total ~1.06 MB)

    style_kernel<<<dim3(1024), dim3(256), 0, stream>>>(dl, dw, db, style);
    w2_kernel  <<<dim3(1024), dim3(256), 0, stream>>>(w, w2);
    demod_kernel<<<dim3(1024), dim3(256), 0, stream>>>(w2, style, dvec);
    conv_kernel<<<dim3(16, 32, 8), dim3(256), 0, stream>>>(x, w, style, dvec, out);
}

// Round 2
// 260.628 us; speedup vs baseline: 12.4281x; 12.4281x over previous
//
#include <hip/hip_runtime.h>
#include <math.h>

// Modulated conv2d (StyleGAN2): B=8, I=O=512, H=W=64, K=3, fp32 in/out.
// R2: bf16 MFMA implicit-GEMM. xs = bf16(x*style) packed padded-NHWC-chunked;
// w packed in exact A-fragment order; conv = 16 k-chunks x 9 taps of
// mfma_f32_16x16x32_bf16. Demod factor computed in fp32 (as R1).

typedef short short8 __attribute__((ext_vector_type(8)));
typedef float floatx4 __attribute__((ext_vector_type(4)));
typedef unsigned short ushort_t;

#define CIN   512
#define COUT  512

// float -> bf16 RNE
__device__ __forceinline__ ushort_t f2bf(float f) {
    union { float f; unsigned u; } v; v.f = f;
    unsigned r = v.u + 0x7fff + ((v.u >> 16) & 1);
    return (ushort_t)(r >> 16);
}

__device__ __forceinline__ void gload_lds16(const void* g, void* l) {
    __builtin_amdgcn_global_load_lds(
        (const __attribute__((address_space(1))) unsigned int*)g,
        (__attribute__((address_space(3))) unsigned int*)l, 16, 0, 0);
}

// ---------- style[b][i] = (dlatents[b] . dense_w[i]) / sqrt(512) + dense_b[i]
__global__ void style_kernel(const float* __restrict__ dl,
                             const float* __restrict__ dw,
                             const float* __restrict__ db,
                             float* __restrict__ style) {
    int gw   = (blockIdx.x * blockDim.x + threadIdx.x) >> 6;
    int lane = threadIdx.x & 63;
    int b = gw >> 9;
    int i = gw & 511;
    const float* dlp = dl + b * 512;
    const float* dwp = dw + (size_t)i * 512;
    float acc = 0.f;
    #pragma unroll
    for (int d = 0; d < 512; d += 64) acc += dlp[d + lane] * dwp[d + lane];
    #pragma unroll
    for (int off = 32; off > 0; off >>= 1) acc += __shfl_down(acc, off, 64);
    if (lane == 0) style[b * 512 + i] = acc * 0.044194173824159216f + db[i];
}

// ---------- w2[o][i] = sum_tap w[o][i][tap]^2
__global__ void w2_kernel(const float* __restrict__ w, float* __restrict__ w2) {
    int idx = blockIdx.x * blockDim.x + threadIdx.x;
    const float* wp = w + (size_t)idx * 9;
    float s = 0.f;
    #pragma unroll
    for (int t = 0; t < 9; t++) s += wp[t] * wp[t];
    w2[idx] = s;
}

// ---------- d[b][o] = rsqrt( (1/4608) * sum_i w2[o][i]*style[b][i]^2 + 1e-8 )
__global__ void demod_kernel(const float* __restrict__ w2,
                             const float* __restrict__ style,
                             float* __restrict__ dvec) {
    int gw   = (blockIdx.x * blockDim.x + threadIdx.x) >> 6;
    int lane = threadIdx.x & 63;
    int b = gw >> 9;
    int o = gw & 511;
    const float* w2p = w2 + (size_t)o * 512;
    const float* stp = style + b * 512;
    float acc = 0.f;
    #pragma unroll
    for (int i = 0; i < 512; i += 64) {
        float s = stp[i + lane];
        acc += w2p[i + lane] * s * s;
    }
    #pragma unroll
    for (int off = 32; off > 0; off >>= 1) acc += __shfl_down(acc, off, 64);
    if (lane == 0)
        dvec[b * 512 + o] = rsqrtf(acc * (1.0f / 4608.0f) + 1e-8f);
}

// ---------- pack w*cs into A-fragment order: wpk[ck16][tap9][osub32][lane64][j8]
// A[m=lane&15][k=(lane>>4)*8+j]; o = osub*16 + (lane&15), i = ck*32 + (lane>>4)*8 + j
__global__ void pack_w_kernel(const float* __restrict__ w, ushort_t* __restrict__ wpk) {
    int t = blockIdx.x * 256 + threadIdx.x;     // 0 .. 294911
    int L  = t & 63;
    int r  = t >> 6;
    int osub = r & 31;
    int r2 = r >> 5;            // ck*9 + tap
    int tap = r2 % 9;
    int ck  = r2 / 9;
    int o = osub * 16 + (L & 15);
    int ibase = ck * 32 + (L >> 4) * 8;
    const float cs = 0.014731391274719738f;     // 1/sqrt(4608)
    short8 v;
    #pragma unroll
    for (int j = 0; j < 8; j++)
        v[j] = (short)f2bf(w[((size_t)o * 512 + ibase + j) * 9 + tap] * cs);
    *(short8*)(wpk + (size_t)t * 8) = v;
}

// ---------- pack x*style (bf16) into padded layout xsg[b8][ck16][khi4][hp66][wp66][j8]
// zero halo at hp/wp == 0 or 65; channel i = ck*32 + khi*8 + j
__global__ void pack_x_kernel(const float* __restrict__ x, const float* __restrict__ style,
                              ushort_t* __restrict__ xsg) {
    int t = blockIdx.x * 256 + threadIdx.x;     // 0 .. 2230271
    int wp = t % 66;
    int t2 = t / 66;
    int hp = t2 % 66;
    int t3 = t2 / 66;
    int khi = t3 & 3;
    int t4 = t3 >> 2;
    int ck = t4 & 15;
    int b  = t4 >> 4;
    short8 v;
    if (hp >= 1 && hp <= 64 && wp >= 1 && wp <= 64) {
        #pragma unroll
        for (int j = 0; j < 8; j++) {
            int i = ck * 32 + khi * 8 + j;
            float f = x[(((size_t)b * 512 + i) * 64 + hp - 1) * 64 + wp - 1] * style[b * 512 + i];
            v[j] = (short)f2bf(f);
        }
    } else {
        #pragma unroll
        for (int j = 0; j < 8; j++) v[j] = 0;
    }
    *(short8*)(xsg + (size_t)t * 8) = v;
}

// ---------- conv: block tile M=128 (8 osubs), N=256 (4 rows x 64 cols)
// grid (16 hquads, 8 b, 4 og); 256 threads = 4 waves; wave = 4 msub x 8 nsub
__global__ __launch_bounds__(256, 2) void conv_mfma_kernel(
        const ushort_t* __restrict__ xsg, const ushort_t* __restrict__ wpk,
        const float* __restrict__ dvec, float* __restrict__ out) {
    __shared__ ushort_t lds_x[4 * 6 * 66 * 8];    // 25344 B: [khi][6 rows][66 cols][8 ch]

    const int tid  = threadIdx.x;
    const int lane = tid & 63;
    const int wv   = tid >> 6;
    const int quad = lane >> 4;
    const int l16  = lane & 15;
    const int hq = blockIdx.x;
    const int b  = blockIdx.y;
    const int og = blockIdx.z;
    const int h0 = hq * 4;

    const int mbase = (wv & 1) * 4;       // 4 msubs per wave
    const int nbase = (wv >> 1) * 8;      // 8 nsubs per wave

    floatx4 acc[4][8];
    #pragma unroll
    for (int i = 0; i < 4; i++)
        #pragma unroll
        for (int j = 0; j < 8; j++) acc[i][j] = (floatx4)(0.f);

    const size_t img_base = (size_t)b * 16 * (4 * 66 * 66 * 8);
    const int bl_base = quad * 3168 + l16 * 8;        // lane part of B-frag lds offset

    for (int ck = 0; ck < 16; ck++) {
        __syncthreads();
        const ushort_t* src = xsg + img_base + (size_t)ck * (4 * 66 * 66 * 8)
                              + h0 * (66 * 8);
        // stage 4 planes x 6 rows x 66 cols x 8ch = 25344 B, contiguous per plane
        for (int off = tid * 16; off < 25344; off += 4096) {
            int khi = off / 6336;
            int rem = off - khi * 6336;
            gload_lds16(src + (size_t)khi * (66 * 66 * 8) + (rem >> 1),
                        (char*)lds_x + off);
        }
        __syncthreads();

        const ushort_t* wck = wpk + (size_t)ck * (9 * 32 * 64 * 8)
                              + (og * 8 + mbase) * (64 * 8) + lane * 8;
        #pragma unroll
        for (int tap = 0; tap < 9; tap++) {
            const int dy = tap / 3, dx = tap % 3;
            short8 afr[4];
            #pragma unroll
            for (int mi = 0; mi < 4; mi++)
                afr[mi] = *(const short8*)(wck + (size_t)tap * (32 * 64 * 8) + mi * (64 * 8));
            #pragma unroll
            for (int q = 0; q < 8; q++) {
                const int nsub = nbase + q;
                const int off = bl_base + ((nsub >> 2) + dy) * 528 + ((nsub & 3) * 16 + dx) * 8;
                const short8 bfr = *(const short8*)&lds_x[off];
                #pragma unroll
                for (int mi = 0; mi < 4; mi++)
                    acc[mi][q] = __builtin_amdgcn_mfma_f32_16x16x32_bf16(
                        afr[mi], bfr, acc[mi][q], 0, 0, 0);
            }
        }
    }

    // epilogue: D col=lane&15 (pixel), row=(lane>>4)*4+reg (o within 16)
    const float* dvb = dvec + b * COUT;
    #pragma unroll
    for (int mi = 0; mi < 4; mi++) {
        const int obase = (og * 8 + mbase + mi) * 16 + quad * 4;
        #pragma unroll
        for (int q = 0; q < 8; q++) {
            const int nsub = nbase + q;
            const int h = h0 + (nsub >> 2);
            const int col = (nsub & 3) * 16 + l16;
            #pragma unroll
            for (int r = 0; r < 4; r++) {
                const int o = obase + r;
                out[(((size_t)b * COUT + o) * 64 + h) * 64 + col] = acc[mi][q][r] * dvb[o];
            }
        }
    }
}

extern "C" void kernel_launch(void* const* d_in, const int* in_sizes, int n_in,
                              void* d_out, int out_size, void* d_ws, size_t ws_size,
                              hipStream_t stream) {
    const float* x  = (const float*)d_in[0];   // [8,512,64,64]
    const float* dl = (const float*)d_in[1];   // [8,512]
    const float* w  = (const float*)d_in[2];   // [512,512,3,3]
    const float* dw = (const float*)d_in[3];   // [512,512]
    const float* db = (const float*)d_in[4];   // [512]
    float* out = (float*)d_out;

    float* style = (float*)d_ws;                               // 4096 f32
    float* dvec  = style + 4096;                               // 4096 f32
    float* w2    = style + 8192;                               // 262144 f32
    ushort_t* wpk = (ushort_t*)((char*)d_ws + (2u << 20));     // 294912*8 bf16 = 4.72 MB
    ushort_t* xsg = (ushort_t*)((char*)d_ws + (8u << 20));     // 2230272*8 bf16 = 35.7 MB

    style_kernel<<<dim3(1024), dim3(256), 0, stream>>>(dl, dw, db, style);
    w2_kernel   <<<dim3(1024), dim3(256), 0, stream>>>(w, w2);
    demod_kernel<<<dim3(1024), dim3(256), 0, stream>>>(w2, style, dvec);
    pack_w_kernel<<<dim3(1152), dim3(256), 0, stream>>>(w, wpk);
    pack_x_kernel<<<dim3(8712), dim3(256), 0, stream>>>(x, style, xsg);
    conv_mfma_kernel<<<dim3(16, 8, 4), dim3(256), 0, stream>>>(xsg, wpk, dvec, out);
}

// Round 3
// 248.097 us; speedup vs baseline: 13.0558x; 1.0505x over previous
//
#include <hip/hip_runtime.h>
#include <math.h>

// Modulated conv2d (StyleGAN2): B=8, I=O=512, H=W=64, K=3, fp32 in/out.
// R3: bf16 MFMA implicit-GEMM + LDS double-buffer (1 barrier/ck) + A-frag
// tap-prefetch; float4 pack_x; fused prologue (3 kernels instead of 5).

typedef short short8 __attribute__((ext_vector_type(8)));
typedef float floatx4 __attribute__((ext_vector_type(4)));
typedef unsigned short ushort_t;

#define COUT  512

// float -> bf16 RNE
__device__ __forceinline__ ushort_t f2bf(float f) {
    union { float f; unsigned u; } v; v.f = f;
    unsigned r = v.u + 0x7fff + ((v.u >> 16) & 1);
    return (ushort_t)(r >> 16);
}

__device__ __forceinline__ void gload_lds16(const void* g, void* l) {
    __builtin_amdgcn_global_load_lds(
        (const __attribute__((address_space(1))) unsigned int*)g,
        (__attribute__((address_space(3))) unsigned int*)l, 16, 0, 0);
}

// ---------- K1: style (blocks 0..1023) + w2 (blocks 1024..2047)
// style[b][i] = (dl[b].dw[i])/sqrt(512) + db[i];  w2[o][i] = sum_tap w^2
__global__ void style_w2_kernel(const float* __restrict__ dl,
                                const float* __restrict__ dw,
                                const float* __restrict__ db,
                                const float* __restrict__ w,
                                float* __restrict__ style,
                                float* __restrict__ w2) {
    if (blockIdx.x < 1024) {
        int gw   = (blockIdx.x * 256 + threadIdx.x) >> 6;
        int lane = threadIdx.x & 63;
        int b = gw >> 9;
        int i = gw & 511;
        const float* dlp = dl + b * 512;
        const float* dwp = dw + (size_t)i * 512;
        float acc = 0.f;
        #pragma unroll
        for (int d = 0; d < 512; d += 64) acc += dlp[d + lane] * dwp[d + lane];
        #pragma unroll
        for (int off = 32; off > 0; off >>= 1) acc += __shfl_down(acc, off, 64);
        if (lane == 0) style[b * 512 + i] = acc * 0.044194173824159216f + db[i];
    } else {
        int idx = (blockIdx.x - 1024) * 256 + threadIdx.x;
        const float* wp = w + (size_t)idx * 9;
        float s = 0.f;
        #pragma unroll
        for (int t = 0; t < 9; t++) s += wp[t] * wp[t];
        w2[idx] = s;
    }
}

// ---------- K2: demod (blocks 0..1023) + pack_w (blocks 1024..2175)
// d[b][o] = rsqrt((1/4608) sum_i w2[o][i]*style[b][i]^2 + 1e-8)
// wpk[ck16][tap9][osub32][lane64][j8], A[m=lane&15][k=(lane>>4)*8+j]
__global__ void demod_packw_kernel(const float* __restrict__ w2,
                                   const float* __restrict__ style,
                                   const float* __restrict__ w,
                                   float* __restrict__ dvec,
                                   ushort_t* __restrict__ wpk) {
    if (blockIdx.x < 1024) {
        int gw   = (blockIdx.x * 256 + threadIdx.x) >> 6;
        int lane = threadIdx.x & 63;
        int b = gw >> 9;
        int o = gw & 511;
        const float* w2p = w2 + (size_t)o * 512;
        const float* stp = style + b * 512;
        float acc = 0.f;
        #pragma unroll
        for (int i = 0; i < 512; i += 64) {
            float s = stp[i + lane];
            acc += w2p[i + lane] * s * s;
        }
        #pragma unroll
        for (int off = 32; off > 0; off >>= 1) acc += __shfl_down(acc, off, 64);
        if (lane == 0)
            dvec[b * 512 + o] = rsqrtf(acc * (1.0f / 4608.0f) + 1e-8f);
    } else {
        int t = (blockIdx.x - 1024) * 256 + threadIdx.x;  // 0 .. 294911
        int L  = t & 63;
        int r  = t >> 6;
        int osub = r & 31;
        int r2 = r >> 5;
        int tap = r2 % 9;
        int ck  = r2 / 9;
        int o = osub * 16 + (L & 15);
        int ibase = ck * 32 + (L >> 4) * 8;
        const float cs = 0.014731391274719738f;   // 1/sqrt(4608)
        short8 v;
        #pragma unroll
        for (int j = 0; j < 8; j++)
            v[j] = (short)f2bf(w[((size_t)o * 512 + ibase + j) * 9 + tap] * cs);
        *(short8*)(wpk + (size_t)t * 8) = v;
    }
}

// ---------- K3: pack x*style (bf16) -> xsg[b8][ck16][khi4][hp66][wp66][j8]
// float4 reads, 64B/thread writes. g=0..15: 4 interior pixels; g=16: col halo.
__global__ void pack_x_kernel(const float* __restrict__ x, const float* __restrict__ style,
                              ushort_t* __restrict__ xsg) {
    int t  = blockIdx.x * 256 + threadIdx.x;   // 0 .. 574463
    int g  = t % 17;
    int t2 = t / 17;
    int hp = t2 % 66;
    int t3 = t2 / 66;
    int khi = t3 & 3;
    int t4 = t3 >> 2;
    int ck = t4 & 15;
    int b  = t4 >> 4;
    size_t rowbase = (((size_t)(b * 16 + ck) * 4 + khi) * 66 + hp) * 66 * 8;
    if (g == 16) {   // wp = 0 and wp = 65 halo columns
        short8 z = (short8)0;
        *(short8*)(xsg + rowbase) = z;
        *(short8*)(xsg + rowbase + 65 * 8) = z;
        return;
    }
    int wp0 = 1 + g * 4;
    short8 v[4];
    if (hp >= 1 && hp <= 64) {
        #pragma unroll
        for (int j = 0; j < 8; j++) {
            int i = ck * 32 + khi * 8 + j;
            const float4 xv = *(const float4*)&x[(((size_t)b * 512 + i) * 64 + hp - 1) * 64 + wp0 - 1];
            const float s = style[b * 512 + i];
            v[0][j] = (short)f2bf(xv.x * s);
            v[1][j] = (short)f2bf(xv.y * s);
            v[2][j] = (short)f2bf(xv.z * s);
            v[3][j] = (short)f2bf(xv.w * s);
        }
    } else {
        #pragma unroll
        for (int p = 0; p < 4; p++)
            #pragma unroll
            for (int j = 0; j < 8; j++) v[p][j] = 0;
    }
    #pragma unroll
    for (int p = 0; p < 4; p++)
        *(short8*)(xsg + rowbase + (size_t)(wp0 + p) * 8) = v[p];
}

// ---------- K4: conv. block M=128 (8 osub16), N=256 (4 rows x 64 cols).
// grid (16 hq, 8 b, 4 og); 4 waves: wave = 4 msub x 8 nsub.
// LDS double-buffered: stage ck+1 while computing ck; 1 barrier per ck.
#define CKSTR  147456   // 9*32*64*8 ushorts
#define TAPSTR 16384    // 32*64*8
__global__ __launch_bounds__(256, 2) void conv_mfma_kernel(
        const ushort_t* __restrict__ xsg, const ushort_t* __restrict__ wpk,
        const float* __restrict__ dvec, float* __restrict__ out) {
    __shared__ ushort_t lds_x[2][4 * 6 * 66 * 8];   // 2 x 25344 B

    const int tid  = threadIdx.x;
    const int lane = tid & 63;
    const int wv   = tid >> 6;
    const int quad = lane >> 4;
    const int l16  = lane & 15;
    const int hq = blockIdx.x;
    const int b  = blockIdx.y;
    const int og = blockIdx.z;
    const int h0 = hq * 4;

    const int mbase = (wv & 1) * 4;
    const int nbase = (wv >> 1) * 8;

    floatx4 acc[4][8];
    #pragma unroll
    for (int i = 0; i < 4; i++)
        #pragma unroll
        for (int j = 0; j < 8; j++) acc[i][j] = (floatx4)(0.f);

    const size_t img_base = (size_t)b * 16 * (4 * 66 * 66 * 8) + h0 * (66 * 8);
    const int bl_base = quad * 3168 + l16 * 8;

    auto stage = [&](int ck, ushort_t* dst) {
        const ushort_t* src = xsg + img_base + (size_t)ck * (4 * 66 * 66 * 8);
        #pragma unroll
        for (int k = 0; k < 7; k++) {
            int off = tid * 16 + k * 4096;
            if (off < 25344) {
                int khi = off / 6336;
                int rem = off - khi * 6336;
                gload_lds16(src + (size_t)khi * (66 * 66 * 8) + (rem >> 1),
                            (char*)dst + off);
            }
        }
    };

    // A-frag pointer: + ck*CKSTR + tap*TAPSTR + mi*512
    const ushort_t* wlane = wpk + (size_t)(og * 8 + mbase) * 512 + lane * 8;
    short8 a_cur[4], a_nxt[4];
    #pragma unroll
    for (int mi = 0; mi < 4; mi++) a_cur[mi] = *(const short8*)(wlane + mi * 512);

    stage(0, lds_x[0]);
    int buf = 0;

    for (int ck = 0; ck < 16; ck++) {
        __syncthreads();                       // stage(ck) done; prev compute done
        if (ck < 15) stage(ck + 1, lds_x[buf ^ 1]);
        const ushort_t* lp  = lds_x[buf];
        const ushort_t* wck = wlane + (size_t)ck * CKSTR;
        #pragma unroll
        for (int tap = 0; tap < 9; tap++) {
            const int dy = tap / 3, dx = tap % 3;
            // prefetch next tap's A-frags (last tap: next ck's tap0)
            const ushort_t* wnx = (tap < 8) ? (wck + (tap + 1) * TAPSTR)
                                            : (wck + (ck < 15 ? CKSTR : 0));
            #pragma unroll
            for (int mi = 0; mi < 4; mi++)
                a_nxt[mi] = *(const short8*)(wnx + mi * 512);
            #pragma unroll
            for (int q = 0; q < 8; q++) {
                const int nsub = nbase + q;
                const int off = bl_base + ((nsub >> 2) + dy) * 528 + ((nsub & 3) * 16 + dx) * 8;
                const short8 bfr = *(const short8*)&lp[off];
                #pragma unroll
                for (int mi = 0; mi < 4; mi++)
                    acc[mi][q] = __builtin_amdgcn_mfma_f32_16x16x32_bf16(
                        a_cur[mi], bfr, acc[mi][q], 0, 0, 0);
            }
            #pragma unroll
            for (int mi = 0; mi < 4; mi++) a_cur[mi] = a_nxt[mi];
        }
        buf ^= 1;
    }

    // epilogue: D col=lane&15 (pixel), row=(lane>>4)*4+reg (o within 16)
    const float* dvb = dvec + b * COUT;
    #pragma unroll
    for (int mi = 0; mi < 4; mi++) {
        const int obase = (og * 8 + mbase + mi) * 16 + quad * 4;
        #pragma unroll
        for (int q = 0; q < 8; q++) {
            const int nsub = nbase + q;
            const int h = h0 + (nsub >> 2);
            const int col = (nsub & 3) * 16 + l16;
            #pragma unroll
            for (int r = 0; r < 4; r++) {
                const int o = obase + r;
                out[(((size_t)b * COUT + o) * 64 + h) * 64 + col] = acc[mi][q][r] * dvb[o];
            }
        }
    }
}

extern "C" void kernel_launch(void* const* d_in, const int* in_sizes, int n_in,
                              void* d_out, int out_size, void* d_ws, size_t ws_size,
                              hipStream_t stream) {
    const float* x  = (const float*)d_in[0];   // [8,512,64,64]
    const float* dl = (const float*)d_in[1];   // [8,512]
    const float* w  = (const float*)d_in[2];   // [512,512,3,3]
    const float* dw = (const float*)d_in[3];   // [512,512]
    const float* db = (const float*)d_in[4];   // [512]
    float* out = (float*)d_out;

    float* style = (float*)d_ws;                               // 4096 f32
    float* dvec  = style + 4096;                               // 4096 f32
    float* w2    = style + 8192;                               // 262144 f32
    ushort_t* wpk = (ushort_t*)((char*)d_ws + (2u << 20));     // 4.72 MB bf16
    ushort_t* xsg = (ushort_t*)((char*)d_ws + (8u << 20));     // 35.7 MB bf16

    style_w2_kernel  <<<dim3(2048), dim3(256), 0, stream>>>(dl, dw, db, w, style, w2);
    demod_packw_kernel<<<dim3(2176), dim3(256), 0, stream>>>(w2, style, w, dvec, wpk);
    pack_x_kernel    <<<dim3(2244), dim3(256), 0, stream>>>(x, style, xsg);
    conv_mfma_kernel <<<dim3(16, 8, 4), dim3(256), 0, stream>>>(xsg, wpk, dvec, out);
}